// Round 1
// baseline (1179.511 us; speedup 1.0000x reference)
//
#include <hip/hip_runtime.h>
#include <math.h>

// ---------------- geometry constants (match reference) ----------------
#define NXg      192
#define NT       200
#define NM       32
#define NRc      8
#define Bc       2
#define PLANES   (Bc * NRc)            // 16 independent planes
#define PLANE_SZ (NXg * NXg)           // 36864
#define TOTAL    (PLANES * PLANE_SZ)   // 589824
#define CEN0     48                    // central 96x96 window start (TOT)
#define CENW     96
#define RING0    25                    // abc_pd
#define RING1    167                   // NXg - abc_pd

struct MeasIdx { int v[NM]; };

// Precompute rf (B x 96 x 96, only region where it's nonzero) and the
// receiver flag table (one byte per pixel: 0 = not a receiver, m+1 = receiver m).
__global__ void precompute_kernel(const float* __restrict__ x,
                                  float* __restrict__ rf,
                                  unsigned char* __restrict__ flag,
                                  MeasIdx meas)
{
    int idx = blockIdx.x * blockDim.x + threadIdx.x;
    if (idx < Bc * CENW * CENW) {
        float xv = x[idx];              // x is (2,1,96,96) flat
        float t = 1.5f / xv;            // bg / x
        rf[idx] = 1.0f - t * t;         // (BGF/bg)^2 == 1 in the central window
    }
    if (idx < NM) {
        flag[meas.v[idx]] = (unsigned char)(idx + 1);
    }
}

// One time step: p_new = 2*p1 - p0 + coef*lap4(p1) + rf*d2j  (periodic wrap).
// Reads pc (= p1), reads+overwrites po (p0 in, p_new out).
// Also scatters the 32 receiver samples of p_new into out[...,j].
__global__ __launch_bounds__(256)
void step_kernel(const float* __restrict__ pc,
                 float* __restrict__ po,
                 const float* __restrict__ P0,
                 const float* __restrict__ rf,
                 const unsigned char* __restrict__ flag,
                 float* __restrict__ out,
                 int j)
{
    int idx = blockIdx.x * blockDim.x + threadIdx.x;
    if (idx >= TOTAL) return;

    int x  = idx % NXg;
    int y  = (idx / NXg) % NXg;
    int pl = idx / PLANE_SZ;            // pl = b*8 + r

    const float* P = pc + (size_t)pl * PLANE_SZ;

    // periodic neighbor indices (match jnp.roll)
    int xm1 = (x == 0)        ? NXg - 1     : x - 1;
    int xm2 = (x <= 1)        ? x + NXg - 2 : x - 2;
    int xp1 = (x == NXg - 1)  ? 0           : x + 1;
    int xp2 = (x >= NXg - 2)  ? x - NXg + 2 : x + 2;
    int ym1 = (y == 0)        ? NXg - 1     : y - 1;
    int ym2 = (y <= 1)        ? y + NXg - 2 : y - 2;
    int yp1 = (y == NXg - 1)  ? 0           : y + 1;
    int yp2 = (y >= NXg - 2)  ? y - NXg + 2 : y + 2;

    const float* row = P + (size_t)y * NXg;
    float c = row[x];

    float lx = (-row[xm2] + 16.0f * row[xm1] - 30.0f * c
                + 16.0f * row[xp1] - row[xp2]) * (1.0f / 12.0f);
    float ly = (-P[(size_t)ym2 * NXg + x] + 16.0f * P[(size_t)ym1 * NXg + x] - 30.0f * c
                + 16.0f * P[(size_t)yp1 * NXg + x] - P[(size_t)yp2 * NXg + x]) * (1.0f / 12.0f);
    float lap = lx + ly;

    // coef = (dt*BGF/dx)^2 ; BGF = 1.5 inside the ring frame, 1e-6 outside
    bool inner = (y >= RING0) && (y < RING1) && (x >= RING0) && (x < RING1);
    float bgf  = inner ? 1.5f : 1e-6f;
    float cf   = 0.3f * bgf;
    cf = cf * cf;

    float pnew = 2.0f * c - po[idx] + cf * lap;

    // source term: nonzero only in the central 96x96 window and for j >= 2
    if (j >= 2 && (unsigned)(y - CEN0) < (unsigned)CENW
               && (unsigned)(x - CEN0) < (unsigned)CENW) {
        int r = pl & 7;
        int b = pl >> 3;
        const float* q = P0 + ((size_t)r * NT + j) * PLANE_SZ + (size_t)y * NXg + x;
        float d2 = q[0] - 2.0f * q[-PLANE_SZ] + q[-2 * PLANE_SZ];
        pnew += rf[(b * CENW + (y - CEN0)) * CENW + (x - CEN0)] * d2;
    }

    po[idx] = pnew;

    unsigned char f = flag[(size_t)y * NXg + x];
    if (f) {
        int m = (int)f - 1;
        out[((size_t)pl * NM + m) * NT + j] = pnew;
    }
}

extern "C" void kernel_launch(void* const* d_in, const int* in_sizes, int n_in,
                              void* d_out, int out_size, void* d_ws, size_t ws_size,
                              hipStream_t stream)
{
    const float* x  = (const float*)d_in[0];   // (2,1,96,96) f32
    const float* P0 = (const float*)d_in[1];   // (1,8,200,192,192) f32
    float* out = (float*)d_out;                // (2,8,32,200) f32

    // workspace layout: two ping-pong field buffers, rf, receiver flags
    float* pA = (float*)d_ws;
    float* pB = pA + TOTAL;
    float* rf = pB + TOTAL;
    unsigned char* flag = (unsigned char*)(rf + Bc * CENW * CENW);

    size_t clear_bytes = (size_t)(2 * TOTAL + Bc * CENW * CENW) * sizeof(float)
                         + (size_t)PLANE_SZ;   // flag bytes
    hipMemsetAsync(d_ws, 0, clear_bytes, stream);

    // receiver flat indices, computed exactly like numpy (float64 -> trunc)
    MeasIdx meas;
    for (int k = 0; k < NM; ++k) {
        double th = 2.0 * M_PI * (double)k / (double)NM;
        int mx = (int)(96.0 + 70.0 * cos(th));
        int my = (int)(96.0 + 70.0 * sin(th));
        meas.v[k] = mx * NXg + my;
    }

    precompute_kernel<<<(Bc * CENW * CENW + 255) / 256, 256, 0, stream>>>(x, rf, flag, meas);

    float* cur = pA;   // p1
    float* old = pB;   // p0 (becomes p_new)
    for (int j = 0; j < NT; ++j) {
        step_kernel<<<TOTAL / 256, 256, 0, stream>>>(cur, old, P0, rf, flag, out, j);
        float* t = cur; cur = old; old = t;
    }
}

// Round 2
// 580.443 us; speedup vs baseline: 2.0321x; 2.0321x over previous
//
#include <hip/hip_runtime.h>
#include <math.h>

// ---------------- geometry constants (match reference) ----------------
#define NXg      192
#define PLANE_SZ (NXg*NXg)            // 36864
#define PLANES   16                   // B(2) * NR(8) independent planes
#define TOTAL    (PLANES*PLANE_SZ)
#define NT       200
#define NM       32
#define CW       96                   // central window width
#define C0       48                   // central window origin
#define W96SQ    (CW*CW)              // 9216
#define EXP      80                   // expanded tile (48 + 2*16)
#define STRIDE   84                   // padded LDS row stride (floats)
#define TILE     48
#define KSTEP    8
#define NLAUNCH  25

struct MeasIdx { int v[NM]; };

typedef float4 f4;
typedef float2 f2;

// rf = 1 - (bg/x)^2 over the central window, per batch (B=2)
__global__ void rf_kernel(const float* __restrict__ x, float* __restrict__ rf){
    int i = blockIdx.x*blockDim.x + threadIdx.x;
    if (i < 2*W96SQ){ float t = 1.5f/x[i]; rf[i] = 1.0f - t*t; }
}

// d2[r][j][wy][wx] = P0[j] - 2 P0[j-1] + P0[j-2] on the central window (0 for j<2)
__global__ void d2_kernel(const float* __restrict__ P0, float* __restrict__ d2){
    int idx = blockIdx.x*blockDim.x + threadIdx.x;
    if (idx >= 8*NT*W96SQ) return;
    int w = idx % W96SQ;
    int j = (idx / W96SQ) % NT;
    int r = idx / (W96SQ*NT);
    float v = 0.f;
    if (j >= 2){
        int wy = w / CW, wx = w % CW;
        size_t base = ((size_t)(r*NT + j))*PLANE_SZ + (size_t)(C0+wy)*NXg + (C0+wx);
        v = P0[base] - 2.f*P0[base - PLANE_SZ] + P0[base - 2*PLANE_SZ];
    }
    d2[idx] = v;
}

__device__ __forceinline__ f4 frow(f2 L, f4 C, f2 Q,
                                   f4 m2, f4 m1, f4 p1, f4 p2,
                                   f4 O, f4 CF, f4 RF, f4 D2)
{
    const float s = 1.0f/12.0f;
    float v0=L.x, v1=L.y, v2=C.x, v3=C.y, v4=C.z, v5=C.w, v6=Q.x, v7=Q.y;
    float lxA = (-v0 + 16.f*v1 - 30.f*v2 + 16.f*v3 - v4)*s;
    float lxB = (-v1 + 16.f*v2 - 30.f*v3 + 16.f*v4 - v5)*s;
    float lxC = (-v2 + 16.f*v3 - 30.f*v4 + 16.f*v5 - v6)*s;
    float lxD = (-v3 + 16.f*v4 - 30.f*v5 + 16.f*v6 - v7)*s;
    float lyA = (-m2.x + 16.f*m1.x - 30.f*v2 + 16.f*p1.x - p2.x)*s;
    float lyB = (-m2.y + 16.f*m1.y - 30.f*v3 + 16.f*p1.y - p2.y)*s;
    float lyC = (-m2.z + 16.f*m1.z - 30.f*v4 + 16.f*p1.z - p2.z)*s;
    float lyD = (-m2.w + 16.f*m1.w - 30.f*v5 + 16.f*p1.w - p2.w)*s;
    f4 r;
    r.x = 2.f*v2 - O.x + CF.x*(lxA+lyA) + RF.x*D2.x;
    r.y = 2.f*v3 - O.y + CF.y*(lxB+lyB) + RF.y*D2.y;
    r.z = 2.f*v4 - O.z + CF.z*(lxC+lyC) + RF.z*D2.z;
    r.w = 2.f*v5 - O.w + CF.w*(lxD+lyD) + RF.w*D2.w;
    return r;
}

// One fused launch: advance KSTEP steps for a 48x48 interior tile of one plane.
// Expanded 80x80 tile (2 time levels) lives in LDS; garbage shrinks 2/step.
__global__ __launch_bounds__(256)
void step_fused(const float* __restrict__ RA, const float* __restrict__ RB,
                float* __restrict__ WA, float* __restrict__ WB,
                const float* __restrict__ d2, const float* __restrict__ rf,
                float* __restrict__ out, int J, MeasIdx meas)
{
    __shared__ float lds0[EXP*STRIDE];
    __shared__ float lds1[EXP*STRIDE];
    const int tid  = threadIdx.x;
    const int pl   = blockIdx.x >> 4;      // plane = b*8 + r
    const int tile = blockIdx.x & 15;
    const int by = tile >> 2, bx = tile & 3;
    const int gy0 = by*TILE - 16, gx0 = bx*TILE - 16;
    const int b = pl >> 3, rch = pl & 7;

    // ---- load expanded 80x80 tiles of both time levels (periodic wrap) ----
    {
        const size_t pbase = (size_t)pl * PLANE_SZ;
        for (int i = tid; i < EXP*(EXP/4); i += 256){   // 80*20 = 1600 float4 groups
            int ly = i / 20, lx0 = (i % 20) * 4;
            int gy = (gy0 + ly + NXg) % NXg;
            int gx = (gx0 + lx0 + NXg) % NXg;           // group never straddles wrap (4 | 192)
            size_t go = pbase + (size_t)gy*NXg + gx;
            *(f4*)&lds0[ly*STRIDE + lx0] = *(const f4*)&RA[go];
            *(f4*)&lds1[ly*STRIDE + lx0] = *(const f4*)&RB[go];
        }
    }

    // ---- per-sub-block cached setup (4 wide x 2 tall; 20x40 = 800 sub-blocks) ----
    int oM2[4],oM1[4],oC[4],oP2[4],oP3[4],oLl[4],oRr[4],d2o[4];
    bool winv[4], valv[4];
    f4 cfa[4], cfb[4], rfa[4], rfb[4];
#pragma unroll
    for (int gi=0; gi<4; ++gi){
        int g = tid + gi*256;
        valv[gi] = (g < 800);
        int gg = valv[gi] ? g : 0;
        int sby = gg/20, sbx = gg%20;
        int ly0 = 2*sby, lx0 = 4*sbx;
        oC [gi] = ly0*STRIDE + lx0;
        oM2[gi] = max(ly0-2,0)*STRIDE + lx0;
        oM1[gi] = max(ly0-1,0)*STRIDE + lx0;
        oP2[gi] = min(ly0+2,EXP-1)*STRIDE + lx0;
        oP3[gi] = min(ly0+3,EXP-1)*STRIDE + lx0;
        oLl[gi] = ly0*STRIDE + max(lx0-2,0);
        oRr[gi] = ly0*STRIDE + min(lx0+4,EXP-2);
        int gy = (gy0 + ly0 + NXg) % NXg;   // even; rows (gy, gy+1) never straddle wrap
        int gx = (gx0 + lx0 + NXg) % NXg;   // multiple of 4
        bool win = (gy>=C0 && gy<C0+CW && gx>=C0 && gx<C0+CW);  // all-or-nothing per sub-block
        winv[gi] = win;
        d2o[gi] = win ? ((gy-C0)*CW + (gx-C0)) : 0;
        if (win){
            const float* rp = rf + ((size_t)b*CW + (gy-C0))*CW + (gx-C0);
            rfa[gi] = *(const f4*)rp;
            rfb[gi] = *(const f4*)(rp + CW);
        } else {
            rfa[gi] = make_float4(0.f,0.f,0.f,0.f);
            rfb[gi] = rfa[gi];
        }
        float cfv0[4], cfv1[4];
#pragma unroll
        for (int ii=0; ii<4; ++ii){
            int gxr = gx + ii;
            bool ix = (gxr>=25 && gxr<167);
            bool i0 = ix && (gy  >=25 && gy  <167);
            bool i1 = ix && (gy+1>=25 && gy+1<167);
            float c0 = 0.3f * (i0 ? 1.5f : 1e-6f);
            float c1 = 0.3f * (i1 ? 1.5f : 1e-6f);
            cfv0[ii] = c0*c0;
            cfv1[ii] = c1*c1;
        }
        cfa[gi] = make_float4(cfv0[0],cfv0[1],cfv0[2],cfv0[3]);
        cfb[gi] = make_float4(cfv1[0],cfv1[1],cfv1[2],cfv1[3]);
    }

    __syncthreads();

    const float* d2base = d2 + ((size_t)rch*NT + J)*W96SQ;

    float* pa = lds0;   // p_{s-2}  (gets overwritten with p_s)
    float* pb = lds1;   // p_{s-1}  (stencil source)

    for (int s=0; s<KSTEP; ++s){
        const int jj = J + s;
        const float* d2s = d2base + s*W96SQ;
#pragma unroll
        for (int gi=0; gi<4; ++gi) if (valv[gi]){
            f4 Rm2 = *(const f4*)&pb[oM2[gi]];
            f4 Rm1 = *(const f4*)&pb[oM1[gi]];
            f4 Rc0 = *(const f4*)&pb[oC[gi]];
            f4 Rc1 = *(const f4*)&pb[oC[gi]+STRIDE];
            f4 Rp2 = *(const f4*)&pb[oP2[gi]];
            f4 Rp3 = *(const f4*)&pb[oP3[gi]];
            f2 L0  = *(const f2*)&pb[oLl[gi]];
            f2 L1  = *(const f2*)&pb[oLl[gi]+STRIDE];
            f2 Q0  = *(const f2*)&pb[oRr[gi]];
            f2 Q1  = *(const f2*)&pb[oRr[gi]+STRIDE];
            f4 O0  = *(const f4*)&pa[oC[gi]];
            f4 O1  = *(const f4*)&pa[oC[gi]+STRIDE];
            f4 D0 = make_float4(0.f,0.f,0.f,0.f), D1 = D0;
            if (winv[gi]){
                const float* dp = d2s + d2o[gi];
                D0 = *(const f4*)dp;
                D1 = *(const f4*)(dp + CW);
            }
            f4 N0 = frow(L0, Rc0, Q0, Rm2, Rm1, Rc1, Rp2, O0, cfa[gi], rfa[gi], D0);
            f4 N1 = frow(L1, Rc1, Q1, Rm1, Rc0, Rp2, Rp3, O1, cfb[gi], rfb[gi], D1);
            *(f4*)&pa[oC[gi]]        = N0;
            *(f4*)&pa[oC[gi]+STRIDE] = N1;
        }
        __syncthreads();
        // receiver scan: pa now holds p_{J+s}; each receiver owned by one tile
        if (tid < NM){
            int rv = meas.v[tid];
            int ry = rv / NXg, rx = rv % NXg;
            int dy = ry - by*TILE, dx = rx - bx*TILE;
            if ((unsigned)dy < TILE && (unsigned)dx < TILE)
                out[((size_t)pl*NM + tid)*NT + jj] = pa[(dy+16)*STRIDE + (dx+16)];
        }
        float* t = pa; pa = pb; pb = t;
    }

    // ---- write back interior of the last two levels (pb = newest) ----
    {
        const size_t pbase = (size_t)pl * PLANE_SZ;
        for (int i = tid; i < TILE*(TILE/4); i += 256){   // 48*12 = 576 groups
            int r  = i / 12, c4 = (i % 12) * 4;
            size_t go = pbase + (size_t)(by*TILE + r)*NXg + (bx*TILE + c4);
            int lo = (r+16)*STRIDE + (c4+16);
            *(f4*)&WB[go] = *(const f4*)&pb[lo];
            *(f4*)&WA[go] = *(const f4*)&pa[lo];
        }
    }
}

extern "C" void kernel_launch(void* const* d_in, const int* in_sizes, int n_in,
                              void* d_out, int out_size, void* d_ws, size_t ws_size,
                              hipStream_t stream)
{
    const float* x  = (const float*)d_in[0];   // (2,1,96,96) f32
    const float* P0 = (const float*)d_in[1];   // (1,8,200,192,192) f32
    float* out = (float*)d_out;                // (2,8,32,200) f32

    float* F   = (float*)d_ws;
    float* f0  = F;
    float* f1  = F + (size_t)TOTAL;
    float* f2p = F + 2*(size_t)TOTAL;
    float* f3p = F + 3*(size_t)TOTAL;
    float* rfb = F + 4*(size_t)TOTAL;
    float* d2b = rfb + 2*W96SQ;               // 8*200*9216 floats (~59 MB)

    // zero the initial read pair (p_{-2} = p_{-1} = 0)
    hipMemsetAsync(F, 0, (size_t)2*TOTAL*sizeof(float), stream);

    rf_kernel<<<(2*W96SQ+255)/256, 256, 0, stream>>>(x, rfb);
    d2_kernel<<<(8*NT*W96SQ+255)/256, 256, 0, stream>>>(P0, d2b);

    MeasIdx meas;
    for (int k=0;k<NM;++k){
        double th = 2.0*M_PI*(double)k/(double)NM;
        int mx = (int)(96.0 + 70.0*cos(th));
        int my = (int)(96.0 + 70.0*sin(th));
        meas.v[k] = mx*NXg + my;
    }

    float *RA=f0, *RB=f1, *WA=f2p, *WB=f3p;
    for (int L=0; L<NLAUNCH; ++L){
        step_fused<<<256, 256, 0, stream>>>(RA,RB,WA,WB,d2b,rfb,out,L*KSTEP,meas);
        float* t;
        t=RA; RA=WA; WA=t;
        t=RB; RB=WB; WB=t;
    }
}

// Round 3
// 439.552 us; speedup vs baseline: 2.6834x; 1.3205x over previous
//
#include <hip/hip_runtime.h>
#include <math.h>

// ---------------- geometry constants ----------------
#define NXg      192
#define PLANE_SZ (NXg*NXg)            // 36864
#define PLANES   16                   // B(2) * NR(8)
#define TOTAL    (PLANES*PLANE_SZ)
#define NT       200
#define NM       32
#define CW       96                   // central window width
#define C0       48                   // central window origin
#define W96SQ    (CW*CW)
#define A0       24                   // active domain [24,168)^2 ; outside ~0 (coef 9e-14)
#define TILE     36                   // interior tile (square), 16 tiles/plane -> 256 blocks
#define HALO     16                   // 2 cells/step * 8 steps
#define EXPW     68                   // TILE + 2*HALO
#define LSTR     72                   // LDS row stride (EXPW + 4 slack for x-halo reads)
#define LROWS    72                   // 2 pad + 68 + 2 pad
#define KSTEP    8
#define NLAUNCH  25

struct MeasIdx { int v[NM]; };
typedef float4 f4;
typedef float2 f2;

// rf = 1 - (bg/x)^2 over the central window, per batch (B=2)
__global__ void rf_kernel(const float* __restrict__ x, float* __restrict__ rf){
    int i = blockIdx.x*blockDim.x + threadIdx.x;
    if (i < 2*W96SQ){ float t = 1.5f/x[i]; rf[i] = 1.0f - t*t; }
}

// d2[r][j][wy][wx] = P0[j] - 2 P0[j-1] + P0[j-2] on the central window (0 for j<2)
__global__ void d2_kernel(const float* __restrict__ P0, float* __restrict__ d2){
    int idx = blockIdx.x*blockDim.x + threadIdx.x;
    if (idx >= 8*NT*W96SQ) return;
    int w = idx % W96SQ;
    int j = (idx / W96SQ) % NT;
    int r = idx / (W96SQ*NT);
    float v = 0.f;
    if (j >= 2){
        int wy = w / CW, wx = w % CW;
        size_t base = ((size_t)(r*NT + j))*PLANE_SZ + (size_t)(C0+wy)*NXg + (C0+wx);
        v = P0[base] - 2.f*P0[base - PLANE_SZ] + P0[base - 2*PLANE_SZ];
    }
    d2[idx] = v;
}

// identical arithmetic/order to the verified round-1/2 kernel
__device__ __forceinline__ f4 frow(f2 L, f4 C, f2 Q,
                                   f4 m2, f4 m1, f4 p1, f4 p2,
                                   f4 O, f4 CF, f4 RF, f4 D2)
{
    const float s = 1.0f/12.0f;
    float v0=L.x, v1=L.y, v2=C.x, v3=C.y, v4=C.z, v5=C.w, v6=Q.x, v7=Q.y;
    float lxA = (-v0 + 16.f*v1 - 30.f*v2 + 16.f*v3 - v4)*s;
    float lxB = (-v1 + 16.f*v2 - 30.f*v3 + 16.f*v4 - v5)*s;
    float lxC = (-v2 + 16.f*v3 - 30.f*v4 + 16.f*v5 - v6)*s;
    float lxD = (-v3 + 16.f*v4 - 30.f*v5 + 16.f*v6 - v7)*s;
    float lyA = (-m2.x + 16.f*m1.x - 30.f*v2 + 16.f*p1.x - p2.x)*s;
    float lyB = (-m2.y + 16.f*m1.y - 30.f*v3 + 16.f*p1.y - p2.y)*s;
    float lyC = (-m2.z + 16.f*m1.z - 30.f*v4 + 16.f*p1.z - p2.z)*s;
    float lyD = (-m2.w + 16.f*m1.w - 30.f*v5 + 16.f*p1.w - p2.w)*s;
    f4 r;
    r.x = 2.f*v2 - O.x + CF.x*(lxA+lyA) + RF.x*D2.x;
    r.y = 2.f*v3 - O.y + CF.y*(lxB+lyB) + RF.y*D2.y;
    r.z = 2.f*v4 - O.z + CF.z*(lxC+lyC) + RF.z*D2.z;
    r.w = 2.f*v5 - O.w + CF.w*(lxD+lyD) + RF.w*D2.w;
    return r;
}

// Advance KSTEP steps of a 36x36 interior tile of one plane, in LDS.
// Active-domain-only: everything outside [24,168)^2 is identically 0.
__global__ __launch_bounds__(512, 2)
void step_fused(const float* __restrict__ RA, const float* __restrict__ RB,
                float* __restrict__ WA, float* __restrict__ WB,
                const float* __restrict__ d2, const float* __restrict__ rf,
                float* __restrict__ out, int J, MeasIdx meas)
{
    __shared__ float lds0[LROWS*LSTR];
    __shared__ float lds1[LROWS*LSTR];
    const int tid = threadIdx.x;
    const int pl  = blockIdx.x >> 4;          // plane = b*8 + r
    const int t   = blockIdx.x & 15;
    const int ty  = t >> 2, tx = t & 3;
    const int gy0 = A0 + ty*TILE - HALO;      // 8 + 36*ty  (always in [8,184))
    const int gx0 = A0 + tx*TILE - HALO;
    const int b   = pl >> 3, rch = pl & 7;
    const size_t pbase = (size_t)pl * PLANE_SZ;

    // ---- load EXPW x EXPW tiles of both time levels (no wrap needed) ----
    for (int i = tid; i < EXPW*(EXPW/4); i += 512){   // 68*17 = 1156 f4 groups
        int ly = i/17, lx4 = (i%17)*4;
        size_t go = pbase + (size_t)(gy0+ly)*NXg + (gx0+lx4);
        *(f4*)&lds0[(ly+2)*LSTR + lx4] = *(const f4*)&RA[go];
        *(f4*)&lds1[(ly+2)*LSTR + lx4] = *(const f4*)&RB[go];
    }

    // ---- per-thread sub-block setup (2 rows x 4 cols; 34x17 = 578 sub-blocks) ----
    int oC[2], d2o[2];
    bool winv[2], valv[2];
    f4 cfa[2], cfb[2], rfa[2], rfbv[2];
#pragma unroll
    for (int gi=0; gi<2; ++gi){
        int g = tid + gi*512;
        valv[gi] = (g < 578);
        int gg = valv[gi] ? g : 0;
        int sby = gg/17, sbx = gg%17;
        int ly0 = 2*sby, lx0 = 4*sbx;
        oC[gi] = (ly0+2)*LSTR + lx0;          // +2: top pad rows
        int gy = gy0 + ly0, gx = gx0 + lx0;   // absolute coords (no wrap)
        bool win = (gy>=C0 && gy<C0+CW && gx>=C0 && gx<C0+CW);  // pair/group never straddles
        winv[gi] = win;
        d2o[gi] = win ? ((gy-C0)*CW + (gx-C0)) : 0;
        if (win){
            const float* rp = rf + ((size_t)b*CW + (gy-C0))*CW + (gx-C0);
            rfa [gi] = *(const f4*)rp;
            rfbv[gi] = *(const f4*)(rp + CW);
        } else {
            rfa [gi] = make_float4(0.f,0.f,0.f,0.f);
            rfbv[gi] = rfa[gi];
        }
        float c0v[4], c1v[4];
#pragma unroll
        for (int ii=0; ii<4; ++ii){
            int gxr = gx + ii;
            bool ix = (gxr>=25 && gxr<167);
            float g0 = 0.3f * ((ix && gy  >=25 && gy  <167) ? 1.5f : 1e-6f);
            float g1 = 0.3f * ((ix && gy+1>=25 && gy+1<167) ? 1.5f : 1e-6f);
            c0v[ii] = g0*g0;
            c1v[ii] = g1*g1;
        }
        cfa[gi] = make_float4(c0v[0],c0v[1],c0v[2],c0v[3]);
        cfb[gi] = make_float4(c1v[0],c1v[1],c1v[2],c1v[3]);
    }

    __syncthreads();

    const float* d2base = d2 + ((size_t)rch*NT + J)*W96SQ;

    float* pa = lds0;   // p_{s-2} (overwritten with p_s)
    float* pb = lds1;   // p_{s-1} (stencil source)

#pragma unroll
    for (int s=0; s<KSTEP; ++s){
        const float* d2s = d2base + s*W96SQ;
#pragma unroll
        for (int gi=0; gi<2; ++gi) if (valv[gi]){
            int c = oC[gi];
            f4 Rm2 = *(const f4*)&pb[c - 2*LSTR];
            f4 Rm1 = *(const f4*)&pb[c -   LSTR];
            f4 Rc0 = *(const f4*)&pb[c];
            f4 Rc1 = *(const f4*)&pb[c +   LSTR];
            f4 Rp2 = *(const f4*)&pb[c + 2*LSTR];
            f4 Rp3 = *(const f4*)&pb[c + 3*LSTR];
            f2 L0  = *(const f2*)&pb[c - 2];
            f2 L1  = *(const f2*)&pb[c + LSTR - 2];
            f2 Q0  = *(const f2*)&pb[c + 4];
            f2 Q1  = *(const f2*)&pb[c + LSTR + 4];
            f4 O0  = *(const f4*)&pa[c];
            f4 O1  = *(const f4*)&pa[c + LSTR];
            f4 D0 = make_float4(0.f,0.f,0.f,0.f), D1 = D0;
            if (winv[gi]){
                const float* dp = d2s + d2o[gi];
                D0 = *(const f4*)dp;
                D1 = *(const f4*)(dp + CW);
            }
            f4 N0 = frow(L0, Rc0, Q0, Rm2, Rm1, Rc1, Rp2, O0, cfa[gi], rfa[gi],  D0);
            f4 N1 = frow(L1, Rc1, Q1, Rm1, Rc0, Rp2, Rp3, O1, cfb[gi], rfbv[gi], D1);
            *(f4*)&pa[c]        = N0;
            *(f4*)&pa[c + LSTR] = N1;
        }
        __syncthreads();
        // receiver gather: pa holds p_{J+s}; each receiver owned by exactly one tile
        if (tid < NM){
            int rv = meas.v[tid];
            int ry = rv / NXg, rx = rv % NXg;
            int dy = ry - (A0 + ty*TILE), dx = rx - (A0 + tx*TILE);
            if ((unsigned)dy < TILE && (unsigned)dx < TILE)
                out[((size_t)pl*NM + tid)*NT + (J+s)] = pa[(dy+HALO+2)*LSTR + (dx+HALO)];
        }
        float* tp = pa; pa = pb; pb = tp;
    }

    // ---- write back interior of the last two levels (pb = newest) ----
    for (int i = tid; i < TILE*(TILE/4); i += 512){   // 36*9 = 324 groups
        int r = i/9, c4 = (i%9)*4;
        size_t go = pbase + (size_t)(A0 + ty*TILE + r)*NXg + (A0 + tx*TILE + c4);
        int lo = (r+HALO+2)*LSTR + (c4+HALO);
        *(f4*)&WB[go] = *(const f4*)&pb[lo];
        *(f4*)&WA[go] = *(const f4*)&pa[lo];
    }
}

extern "C" void kernel_launch(void* const* d_in, const int* in_sizes, int n_in,
                              void* d_out, int out_size, void* d_ws, size_t ws_size,
                              hipStream_t stream)
{
    const float* x  = (const float*)d_in[0];   // (2,1,96,96) f32
    const float* P0 = (const float*)d_in[1];   // (1,8,200,192,192) f32
    float* out = (float*)d_out;                // (2,8,32,200) f32

    float* F   = (float*)d_ws;
    float* f0  = F;
    float* f1  = F + (size_t)TOTAL;
    float* f2p = F + 2*(size_t)TOTAL;
    float* f3p = F + 3*(size_t)TOTAL;
    float* rfb = F + 4*(size_t)TOTAL;
    float* d2b = rfb + 2*W96SQ;               // 8*200*9216 floats (~59 MB)

    // zero ALL four field buffers: outer cells are never written and must stay 0
    hipMemsetAsync(F, 0, (size_t)4*TOTAL*sizeof(float), stream);

    rf_kernel<<<(2*W96SQ+255)/256, 256, 0, stream>>>(x, rfb);
    d2_kernel<<<(8*NT*W96SQ+255)/256, 256, 0, stream>>>(P0, d2b);

    MeasIdx meas;
    for (int k=0;k<NM;++k){
        double th = 2.0*M_PI*(double)k/(double)NM;
        int mx = (int)(96.0 + 70.0*cos(th));
        int my = (int)(96.0 + 70.0*sin(th));
        meas.v[k] = mx*NXg + my;
    }

    float *RA=f0, *RB=f1, *WA=f2p, *WB=f3p;
    for (int L=0; L<NLAUNCH; ++L){
        step_fused<<<256, 512, 0, stream>>>(RA,RB,WA,WB,d2b,rfb,out,L*KSTEP,meas);
        float* tsw;
        tsw=RA; RA=WA; WA=tsw;
        tsw=RB; RB=WB; WB=tsw;
    }
}

// Round 4
// 324.493 us; speedup vs baseline: 3.6349x; 1.3546x over previous
//
#include <hip/hip_runtime.h>
#include <math.h>

// ---------------- geometry constants ----------------
#define NXg      192
#define PLANE_SZ (NXg*NXg)            // 36864
#define PLANES   16                   // B(2) * NR(8)
#define TOTAL    (PLANES*PLANE_SZ)
#define NT       200
#define NM       32
#define CW       96                   // central window width
#define C0       48                   // central window origin
#define W96SQ    (CW*CW)
#define A0       24                   // active domain [24,168)^2 ; outside ~0 (coef 9e-14)
#define TILE     36                   // interior tile, 16 tiles/plane -> 256 blocks
#define HALO     16                   // 2 cells/step * 8 steps
#define EXPW     68                   // TILE + 2*HALO
#define LSTR     72                   // LDS row stride (EXPW + 4 slack for x-halo reads)
#define LROWS    72                   // 2 pad + 68 + 2 pad
#define KSTEP    8
#define NLAUNCH  25

struct MeasIdx { int v[NM]; };
typedef float4 f4;
typedef float2 f2;

// rf = 1 - (bg/x)^2 over the central window, per batch (B=2)
__global__ void rf_kernel(const float* __restrict__ x, float* __restrict__ rf){
    int i = blockIdx.x*blockDim.x + threadIdx.x;
    if (i < 2*W96SQ){ float t = 1.5f/x[i]; rf[i] = 1.0f - t*t; }
}

// d2[r][j][wy][wx] = P0[j] - 2 P0[j-1] + P0[j-2] on the central window (0 for j<2)
__global__ void d2_kernel(const float* __restrict__ P0, float* __restrict__ d2){
    int idx = blockIdx.x*blockDim.x + threadIdx.x;
    if (idx >= 8*NT*W96SQ) return;
    int w = idx % W96SQ;
    int j = (idx / W96SQ) % NT;
    int r = idx / (W96SQ*NT);
    float v = 0.f;
    if (j >= 2){
        int wy = w / CW, wx = w % CW;
        size_t base = ((size_t)(r*NT + j))*PLANE_SZ + (size_t)(C0+wy)*NXg + (C0+wx);
        v = P0[base] - 2.f*P0[base - PLANE_SZ] + P0[base - 2*PLANE_SZ];
    }
    d2[idx] = v;
}

// identical arithmetic/order to the verified round-1/2/3 kernel
__device__ __forceinline__ f4 frow(f2 L, f4 C, f2 Q,
                                   f4 m2, f4 m1, f4 p1, f4 p2,
                                   f4 O, f4 CF, f4 RF, f4 D2)
{
    const float s = 1.0f/12.0f;
    float v0=L.x, v1=L.y, v2=C.x, v3=C.y, v4=C.z, v5=C.w, v6=Q.x, v7=Q.y;
    float lxA = (-v0 + 16.f*v1 - 30.f*v2 + 16.f*v3 - v4)*s;
    float lxB = (-v1 + 16.f*v2 - 30.f*v3 + 16.f*v4 - v5)*s;
    float lxC = (-v2 + 16.f*v3 - 30.f*v4 + 16.f*v5 - v6)*s;
    float lxD = (-v3 + 16.f*v4 - 30.f*v5 + 16.f*v6 - v7)*s;
    float lyA = (-m2.x + 16.f*m1.x - 30.f*v2 + 16.f*p1.x - p2.x)*s;
    float lyB = (-m2.y + 16.f*m1.y - 30.f*v3 + 16.f*p1.y - p2.y)*s;
    float lyC = (-m2.z + 16.f*m1.z - 30.f*v4 + 16.f*p1.z - p2.z)*s;
    float lyD = (-m2.w + 16.f*m1.w - 30.f*v5 + 16.f*p1.w - p2.w)*s;
    f4 r;
    r.x = 2.f*v2 - O.x + CF.x*(lxA+lyA) + RF.x*D2.x;
    r.y = 2.f*v3 - O.y + CF.y*(lxB+lyB) + RF.y*D2.y;
    r.z = 2.f*v4 - O.z + CF.z*(lxC+lyC) + RF.z*D2.z;
    r.w = 2.f*v5 - O.w + CF.w*(lxD+lyD) + RF.w*D2.w;
    return r;
}

// Advance KSTEP steps of a 36x36 interior tile of one plane, in LDS.
// Shrink-region masking: at loop step s only cells in [2s+2, 65-2s]^2 of the
// expanded tile need computing; per-thread sMax = last step this sub-block
// is active. Center rows + O term carried in registers; d2 prefetched 1 step.
__global__ __launch_bounds__(512, 2)
void step_fused(const float* __restrict__ RA, const float* __restrict__ RB,
                float* __restrict__ WA, float* __restrict__ WB,
                const float* __restrict__ d2, const float* __restrict__ rf,
                float* __restrict__ out, int J, MeasIdx meas)
{
    __shared__ float lds0[LROWS*LSTR];
    __shared__ float lds1[LROWS*LSTR];
    const int tid = threadIdx.x;
    const int pl  = blockIdx.x >> 4;          // plane = b*8 + r
    const int t   = blockIdx.x & 15;
    const int ty  = t >> 2, tx = t & 3;
    const int gy0 = A0 + ty*TILE - HALO;      // always in [8,184)
    const int gx0 = A0 + tx*TILE - HALO;
    const int b   = pl >> 3, rch = pl & 7;
    const size_t pbase = (size_t)pl * PLANE_SZ;

    // ---- load EXPW x EXPW tiles of both time levels ----
    for (int i = tid; i < EXPW*(EXPW/4); i += 512){   // 68*17 = 1156 f4 groups
        int ly = i/17, lx4 = (i%17)*4;
        size_t go = pbase + (size_t)(gy0+ly)*NXg + (gx0+lx4);
        *(f4*)&lds0[(ly+2)*LSTR + lx4] = *(const f4*)&RA[go];
        *(f4*)&lds1[(ly+2)*LSTR + lx4] = *(const f4*)&RB[go];
    }

    // ---- per-thread sub-block setup (2 rows x 4 cols; 34x17 = 578 sub-blocks) ----
    int oC[2], d2o[2], sMax[2];
    bool winv[2];
    f4 cfa[2], cfb[2], rfa[2], rfbv[2];
#pragma unroll
    for (int gi=0; gi<2; ++gi){
        int g = tid + gi*512;
        bool val = (g < 578);
        int gg = val ? g : 0;
        int sby = gg/17, sbx = gg%17;
        int ly0 = 2*sby, lx0 = 4*sbx;
        oC[gi] = (ly0+2)*LSTR + lx0;          // +2: top pad rows
        // last active step: sub-block must intersect [2s+2, 65-2s] in both dims
        int s1 = (ly0-1) >> 1;                // ly0+1 >= 2s+2
        int s2 = (65-ly0) >> 1;               // ly0   <= 65-2s
        int s3 = (lx0+1) >> 1;                // lx0+3 >= 2s+2
        int s4 = (65-lx0) >> 1;               // lx0   <= 65-2s
        int sm = min(min(s1,s2), min(s3,s4));
        sMax[gi] = val ? sm : -1;
        int gy = gy0 + ly0, gx = gx0 + lx0;   // absolute coords
        bool win = (gy>=C0 && gy<C0+CW && gx>=C0 && gx<C0+CW);
        winv[gi] = win;
        d2o[gi] = win ? ((gy-C0)*CW + (gx-C0)) : 0;
        if (win){
            const float* rp = rf + ((size_t)b*CW + (gy-C0))*CW + (gx-C0);
            rfa [gi] = *(const f4*)rp;
            rfbv[gi] = *(const f4*)(rp + CW);
        } else {
            rfa [gi] = make_float4(0.f,0.f,0.f,0.f);
            rfbv[gi] = rfa[gi];
        }
        float c0v[4], c1v[4];
#pragma unroll
        for (int ii=0; ii<4; ++ii){
            int gxr = gx + ii;
            bool ix = (gxr>=25 && gxr<167);
            float g0 = 0.3f * ((ix && gy  >=25 && gy  <167) ? 1.5f : 1e-6f);
            float g1 = 0.3f * ((ix && gy+1>=25 && gy+1<167) ? 1.5f : 1e-6f);
            c0v[ii] = g0*g0;
            c1v[ii] = g1*g1;
        }
        cfa[gi] = make_float4(c0v[0],c0v[1],c0v[2],c0v[3]);
        cfb[gi] = make_float4(c1v[0],c1v[1],c1v[2],c1v[3]);
    }

    __syncthreads();

    // center rows of both levels, register-carried (bit-identical to LDS copies)
    f4 OA0[2], OA1[2], OB0[2], OB1[2];
#pragma unroll
    for (int gi=0; gi<2; ++gi){
        OA0[gi] = *(const f4*)&lds0[oC[gi]];
        OA1[gi] = *(const f4*)&lds0[oC[gi]+LSTR];
        OB0[gi] = *(const f4*)&lds1[oC[gi]];
        OB1[gi] = *(const f4*)&lds1[oC[gi]+LSTR];
    }

    const float* d2base = d2 + ((size_t)rch*NT + J)*W96SQ;

    // prefetch d2 for step 0
    f4 Dn0[2], Dn1[2];
#pragma unroll
    for (int gi=0; gi<2; ++gi){
        Dn0[gi] = make_float4(0.f,0.f,0.f,0.f); Dn1[gi] = Dn0[gi];
        if (winv[gi] && sMax[gi] >= 0){
            const float* dp = d2base + d2o[gi];
            Dn0[gi] = *(const f4*)dp;
            Dn1[gi] = *(const f4*)(dp + CW);
        }
    }

#pragma unroll
    for (int s=0; s<KSTEP; ++s){
        float* pa = (s&1) ? lds1 : lds0;      // level being overwritten with p_s
        float* pb = (s&1) ? lds0 : lds1;      // stencil source p_{s-1}
#pragma unroll
        for (int gi=0; gi<2; ++gi){
            if (s <= sMax[gi]){
                int c = oC[gi];
                f4 C0r = (s&1) ? OA0[gi] : OB0[gi];   // pb center rows (own)
                f4 C1r = (s&1) ? OA1[gi] : OB1[gi];
                f4 O0  = (s&1) ? OB0[gi] : OA0[gi];   // pa center rows (own, p_{s-2})
                f4 O1  = (s&1) ? OB1[gi] : OA1[gi];
                f4 Rm2 = *(const f4*)&pb[c - 2*LSTR];
                f4 Rm1 = *(const f4*)&pb[c -   LSTR];
                f4 Rp2 = *(const f4*)&pb[c + 2*LSTR];
                f4 Rp3 = *(const f4*)&pb[c + 3*LSTR];
                f2 L0  = *(const f2*)&pb[c - 2];
                f2 L1  = *(const f2*)&pb[c + LSTR - 2];
                f2 Q0  = *(const f2*)&pb[c + 4];
                f2 Q1  = *(const f2*)&pb[c + LSTR + 4];
                f4 D0 = Dn0[gi], D1 = Dn1[gi];
                f4 N0 = frow(L0, C0r, Q0, Rm2, Rm1, C1r, Rp2, O0, cfa[gi], rfa[gi],  D0);
                f4 N1 = frow(L1, C1r, Q1, Rm1, C0r, Rp2, Rp3, O1, cfb[gi], rfbv[gi], D1);
                *(f4*)&pa[c]        = N0;
                *(f4*)&pa[c + LSTR] = N1;
                if (s&1){ OB0[gi]=N0; OB1[gi]=N1; } else { OA0[gi]=N0; OA1[gi]=N1; }
            }
            // prefetch d2 for step s+1 (before the barrier -> latency hidden)
            if (s+1 < KSTEP && winv[gi] && (s+1) <= sMax[gi]){
                const float* dp = d2base + (size_t)(s+1)*W96SQ + d2o[gi];
                Dn0[gi] = *(const f4*)dp;
                Dn1[gi] = *(const f4*)(dp + CW);
            }
        }
        __syncthreads();
        // receiver gather: pa holds p_{J+s}; each receiver owned by exactly one tile
        if (tid < NM){
            int rv = meas.v[tid];
            int ry = rv / NXg, rx = rv % NXg;
            int dy = ry - (A0 + ty*TILE), dx = rx - (A0 + tx*TILE);
            if ((unsigned)dy < TILE && (unsigned)dx < TILE)
                out[((size_t)pl*NM + tid)*NT + (J+s)] = pa[(dy+HALO+2)*LSTR + (dx+HALO)];
        }
    }

    // ---- write back interior of the last two levels ----
    // KSTEP=8: s=7 (odd) wrote lds1 -> lds1 = newest p_{J+7}, lds0 = p_{J+6}
    for (int i = tid; i < TILE*(TILE/4); i += 512){   // 36*9 = 324 groups
        int r = i/9, c4 = (i%9)*4;
        size_t go = pbase + (size_t)(A0 + ty*TILE + r)*NXg + (A0 + tx*TILE + c4);
        int lo = (r+HALO+2)*LSTR + (c4+HALO);
        *(f4*)&WB[go] = *(const f4*)&lds1[lo];
        *(f4*)&WA[go] = *(const f4*)&lds0[lo];
    }
}

extern "C" void kernel_launch(void* const* d_in, const int* in_sizes, int n_in,
                              void* d_out, int out_size, void* d_ws, size_t ws_size,
                              hipStream_t stream)
{
    const float* x  = (const float*)d_in[0];   // (2,1,96,96) f32
    const float* P0 = (const float*)d_in[1];   // (1,8,200,192,192) f32
    float* out = (float*)d_out;                // (2,8,32,200) f32

    float* F   = (float*)d_ws;
    float* f0  = F;
    float* f1  = F + (size_t)TOTAL;
    float* f2p = F + 2*(size_t)TOTAL;
    float* f3p = F + 3*(size_t)TOTAL;
    float* rfb = F + 4*(size_t)TOTAL;
    float* d2b = rfb + 2*W96SQ;               // 8*200*9216 floats (~59 MB)

    // zero ALL four field buffers: outer cells are never written and must stay 0
    hipMemsetAsync(F, 0, (size_t)4*TOTAL*sizeof(float), stream);

    rf_kernel<<<(2*W96SQ+255)/256, 256, 0, stream>>>(x, rfb);
    d2_kernel<<<(8*NT*W96SQ+255)/256, 256, 0, stream>>>(P0, d2b);

    MeasIdx meas;
    for (int k=0;k<NM;++k){
        double th = 2.0*M_PI*(double)k/(double)NM;
        int mx = (int)(96.0 + 70.0*cos(th));
        int my = (int)(96.0 + 70.0*sin(th));
        meas.v[k] = mx*NXg + my;
    }

    float *RA=f0, *RB=f1, *WA=f2p, *WB=f3p;
    for (int L=0; L<NLAUNCH; ++L){
        step_fused<<<256, 512, 0, stream>>>(RA,RB,WA,WB,d2b,rfb,out,L*KSTEP,meas);
        float* tsw;
        tsw=RA; RA=WA; WA=tsw;
        tsw=RB; RB=WB; WB=tsw;
    }
}